// Round 8
// baseline (402.522 us; speedup 1.0000x reference)
//
#include <hip/hip_runtime.h>
#include <hip/hip_cooperative_groups.h>
#include <stdint.h>
#include <stddef.h>

namespace cg = cooperative_groups;

// b=4, n=1024, dim=512, heads=8, dh=64. qkv ws: [4096][1024] bf16 = Q|K only,
// q pre-scaled by 1/16; V transposed to vt[b][h][64][1024] bf16.
// Single cooperative kernel: convert -> gemm_qkv -> entmax attn -> gemm_out
// with grid.sync() between phases (kills ~15us/launch serialization bubbles).

typedef __attribute__((ext_vector_type(4))) float f32x4;
typedef __attribute__((ext_vector_type(8))) short bf16x8;
typedef __attribute__((ext_vector_type(4))) uint32_t u32x4;
typedef __attribute__((ext_vector_type(2))) uint32_t u32x2;

__device__ inline unsigned short f2bf(float f) {
    union { float f; uint32_t u; } cv; cv.f = f;
    uint32_t u = cv.u;
    return (unsigned short)((u + 0x7fffu + ((u >> 16) & 1u)) >> 16);
}
__device__ inline uint32_t packbf2(float lo, float hi) {
    return (uint32_t)f2bf(lo) | ((uint32_t)f2bf(hi) << 16);
}
__device__ inline void gl_lds16(const short* g, short* l) {
    __builtin_amdgcn_global_load_lds(
        (const __attribute__((address_space(1))) void*)g,
        (__attribute__((address_space(3))) void*)l, 16, 0, 0);
}

// ---------------------------------------------------------------------------
// Phase 0 unit: bid<1024: x fp32->bf16 (2048 elems); else 32x32 weight
// transpose tile (wqkv: 768 tiles, wout: 256 tiles).
// ---------------------------------------------------------------------------
__device__ __forceinline__ void convert_unit(int bid, int t,
        const float* __restrict__ x, const float* __restrict__ wqkv,
        const float* __restrict__ wout, short* __restrict__ xb,
        short* __restrict__ wqkvt, short* __restrict__ woutt,
        unsigned char* smemraw) {
    if (bid < 1024) {
        int base = bid * 2048 + t * 8;
        f32x4 v0 = *(const f32x4*)(x + base);
        f32x4 v1 = *(const f32x4*)(x + base + 4);
        u32x4 o = {packbf2(v0[0], v0[1]), packbf2(v0[2], v0[3]),
                   packbf2(v1[0], v1[1]), packbf2(v1[2], v1[3])};
        *(u32x4*)(xb + base) = o;
        return;
    }
    float (*tl)[33] = (float (*)[33])smemraw;
    const float* src; short* dst; int NC, tn, tk;
    if (bid < 1024 + 768) {
        int idx = bid - 1024; tn = idx % 48; tk = idx / 48; src = wqkv; dst = wqkvt; NC = 1536;
    } else {
        int idx = bid - 1792; tn = idx % 16; tk = idx / 16; src = wout; dst = woutt; NC = 512;
    }
    __syncthreads();                        // protect tl across grid-stride units
    const int row = t >> 3, c4 = (t & 7) * 4;
    f32x4 v = *(const f32x4*)(src + (size_t)(tk * 32 + row) * NC + tn * 32 + c4);
    tl[row][c4 + 0] = v[0]; tl[row][c4 + 1] = v[1];
    tl[row][c4 + 2] = v[2]; tl[row][c4 + 3] = v[3];
    __syncthreads();
    float a = tl[c4 + 0][row], b = tl[c4 + 1][row];
    float c = tl[c4 + 2][row], d = tl[c4 + 3][row];
    u32x2 o = {packbf2(a, b), packbf2(c, d)};
    *(u32x2*)(dst + (size_t)(tn * 32 + row) * 512 + tk * 32 + c4) = o;
}

// ---------------------------------------------------------------------------
// 64m x 128n bf16 MFMA tile, BK=32 (r3-verified). MODE 0: -> qkv_b [.][1024]
// (bn<4 q *1/16, bn 4..7 k) / vt scatter (bn>=8). MODE 1: fp32 [.][512].
// ---------------------------------------------------------------------------
template<int MODE>
__device__ __forceinline__ void gemm_tile(const short* __restrict__ A,
        const short* __restrict__ Bt, short* __restrict__ qkv_b,
        short* __restrict__ vt, float* __restrict__ of,
        int bm, int bn, int t, unsigned char* smemraw) {
    short* As = (short*)smemraw;            // 64*32 = 4 KB
    short* Bs = (short*)(smemraw + 4096);   // 128*32 = 8 KB
    const int lane = t & 63;
    const int wv = t >> 6;
    const int quad = lane >> 4;
    const int l16 = lane & 15;
    const int wm = (wv & 1) * 32, wn = (wv >> 1) * 64;

    f32x4 acc[2][4];
    #pragma unroll
    for (int i = 0; i < 2; i++)
        #pragma unroll
        for (int j = 0; j < 4; j++) acc[i][j] = (f32x4){0.f, 0.f, 0.f, 0.f};

    const int sr = t >> 2, sc = (t & 3) * 8;
    for (int kt = 0; kt < 16; kt++) {
        gl_lds16(A + (size_t)(bm * 64 + sr) * 512 + kt * 32 + sc, As + t * 8);
        #pragma unroll
        for (int i = 0; i < 2; i++)
            gl_lds16(Bt + (size_t)(bn * 128 + 64 * i + sr) * 512 + kt * 32 + sc,
                     Bs + 64 * i * 32 + t * 8);
        __syncthreads();
        bf16x8 af[2], bfr[4];
        #pragma unroll
        for (int mi = 0; mi < 2; mi++)
            af[mi] = *(const bf16x8*)(As + (wm + mi * 16 + l16) * 32 + quad * 8);
        #pragma unroll
        for (int ni = 0; ni < 4; ni++)
            bfr[ni] = *(const bf16x8*)(Bs + (wn + ni * 16 + l16) * 32 + quad * 8);
        #pragma unroll
        for (int mi = 0; mi < 2; mi++)
            #pragma unroll
            for (int ni = 0; ni < 4; ni++)
                acc[mi][ni] = __builtin_amdgcn_mfma_f32_16x16x32_bf16(af[mi], bfr[ni], acc[mi][ni], 0, 0, 0);
        __syncthreads();
    }

    if (MODE == 0) {
        if (bn < 8) {
            const float scq = (bn < 4) ? 0.0625f : 1.0f;
            #pragma unroll
            for (int mi = 0; mi < 2; mi++)
                #pragma unroll
                for (int ni = 0; ni < 4; ni++)
                    #pragma unroll
                    for (int rg = 0; rg < 4; rg++)
                        qkv_b[(size_t)(bm * 64 + wm + mi * 16 + quad * 4 + rg) * 1024
                              + bn * 128 + wn + ni * 16 + l16] = (short)f2bf(acc[mi][ni][rg] * scq);
        } else {
            #pragma unroll
            for (int mi = 0; mi < 2; mi++) {
                int rowb = bm * 64 + wm + mi * 16 + quad * 4;
                int bbb = rowb >> 10, j = rowb & 1023;
                #pragma unroll
                for (int ni = 0; ni < 4; ni++) {
                    int vcol = bn * 128 + wn + ni * 16 + l16 - 1024;   // 0..511
                    int hh = vcol >> 6, dd = vcol & 63;
                    u32x2 pk = {packbf2(acc[mi][ni][0], acc[mi][ni][1]),
                                packbf2(acc[mi][ni][2], acc[mi][ni][3])};
                    *(u32x2*)(vt + ((size_t)((bbb * 8 + hh) * 64 + dd)) * 1024 + j) = pk;
                }
            }
        }
    } else {
        #pragma unroll
        for (int mi = 0; mi < 2; mi++)
            #pragma unroll
            for (int ni = 0; ni < 4; ni++)
                #pragma unroll
                for (int rg = 0; rg < 4; rg++)
                    of[(size_t)(bm * 64 + wm + mi * 16 + quad * 4 + rg) * 512
                       + bn * 128 + wn + ni * 16 + l16] = acc[mi][ni][rg];
    }
}

// ---------------------------------------------------------------------------
// Dense entmax-1.5 attention unit (r6-verified), 16 query rows.
// Column-chunked score->transpose (no spill), barrier-free Newton, MFMA PV.
// ---------------------------------------------------------------------------
__device__ __forceinline__ void attn_unit(int bid, int t,
        const short* __restrict__ qkv, const short* __restrict__ vt,
        short* __restrict__ ohead, unsigned char* smemraw) {
    short* P_lds = (short*)smemraw;         // 16*1032 shorts = 33024 B
    float* tbuf = (float*)smemraw;          // [16][268] overlay
    float* osum = (float*)smemraw;

    const int lane = t & 63;
    const int wv = t >> 6;
    const int quad = lane >> 4;
    const int l16 = lane & 15;

    const int xcd = bid & 7;
    const int g = bid >> 3;
    const int hb = xcd * 4 + (g >> 6);      // 0..31
    const int rt = g & 63;
    const int bb = hb >> 3, hh = hb & 7;
    const int r0 = rt * 16;

    bf16x8 a0, a1;
    {
        const short* qp = qkv + (size_t)(bb * 1024 + r0 + l16) * 1024 + hh * 64 + quad * 8;
        a0 = *(const bf16x8*)qp;
        a1 = *(const bf16x8*)(qp + 32);
    }

    float zT[64];
    const short* kb0 = qkv + (size_t)(bb * 1024) * 1024 + 512 + hh * 64 + quad * 8;
    const int rown = quad * 4 + wv;
    for (int ci = 0; ci < 4; ci++) {
        f32x4 zc[4];
        #pragma unroll
        for (int f = 0; f < 4; f++) {
            int supl = f >> 1, jj = f & 1;
            int j0 = (ci * 2 + supl) * 128 + (wv + 4 * jj) * 16 + l16;
            const short* kp = kb0 + (size_t)j0 * 1024;
            bf16x8 b0 = *(const bf16x8*)kp;
            bf16x8 b1 = *(const bf16x8*)(kp + 32);
            f32x4 acc = {0.f, 0.f, 0.f, 0.f};
            acc = __builtin_amdgcn_mfma_f32_16x16x32_bf16(a0, b0, acc, 0, 0, 0);
            acc = __builtin_amdgcn_mfma_f32_16x16x32_bf16(a1, b1, acc, 0, 0, 0);
            zc[f] = acc;
        }
        __syncthreads();
        #pragma unroll
        for (int f = 0; f < 4; f++) {
            int supl = f >> 1, jj = f & 1;
            int colc = supl * 128 + (wv + 4 * jj) * 16 + l16;
            #pragma unroll
            for (int rg = 0; rg < 4; rg++)
                tbuf[(quad * 4 + rg) * 268 + colc] = zc[f][rg];
        }
        __syncthreads();
        #pragma unroll
        for (int i = 0; i < 4; i++) {
            f32x4 v = *(const f32x4*)(tbuf + rown * 268 + i * 64 + l16 * 4);
            zT[ci * 16 + i * 4 + 0] = v[0]; zT[ci * 16 + i * 4 + 1] = v[1];
            zT[ci * 16 + i * 4 + 2] = v[2]; zT[ci * 16 + i * 4 + 3] = v[3];
        }
    }
    __syncthreads();

    float tau;
    {
        float m0 = zT[0], m1 = zT[1], m2 = zT[2], m3 = zT[3];
        float p0 = zT[0], p1 = zT[1], p2 = zT[2], p3 = zT[3];
        float q0 = zT[0] * zT[0], q1 = zT[1] * zT[1], q2 = zT[2] * zT[2], q3 = zT[3] * zT[3];
        #pragma unroll
        for (int i = 1; i < 16; i++) {
            float v0 = zT[i * 4], v1 = zT[i * 4 + 1], v2 = zT[i * 4 + 2], v3 = zT[i * 4 + 3];
            m0 = fmaxf(m0, v0); m1 = fmaxf(m1, v1); m2 = fmaxf(m2, v2); m3 = fmaxf(m3, v3);
            p0 += v0; p1 += v1; p2 += v2; p3 += v3;
            q0 = fmaf(v0, v0, q0); q1 = fmaf(v1, v1, q1);
            q2 = fmaf(v2, v2, q2); q3 = fmaf(v3, v3, q3);
        }
        float mx = fmaxf(fmaxf(m0, m1), fmaxf(m2, m3));
        float s1 = (p0 + p1) + (p2 + p3);
        float s2 = (q0 + q1) + (q2 + q3);
        #pragma unroll
        for (int s = 1; s < 16; s <<= 1) {
            mx = fmaxf(mx, __shfl_xor(mx, s, 64));
            s1 += __shfl_xor(s1, s, 64);
            s2 += __shfl_xor(s2, s, 64);
        }
        float mean = s1 * (1.0f / 1024.0f);
        float disc = fmaxf(mean * mean - (s2 - 1.0f) * (1.0f / 1024.0f), 0.0f);
        tau = mean - __builtin_sqrtf(disc);
        tau = fminf(tau, mx - 0.03125f);    // tau* <= mx - 1/sqrt(n)
        tau = fmaxf(tau, mx - 1.0f);        // tau* >= mx - 1
    }

    for (int it = 0; it < 8; it++) {
        float a0s = 0.f, a1s = 0.f, a2s = 0.f, a3s = 0.f;
        float b0s = 0.f, b1s = 0.f, b2s = 0.f, b3s = 0.f;
        #pragma unroll
        for (int i = 0; i < 16; i++) {
            float r0 = fmaxf(zT[i * 4] - tau, 0.f);
            float r1 = fmaxf(zT[i * 4 + 1] - tau, 0.f);
            float r2 = fmaxf(zT[i * 4 + 2] - tau, 0.f);
            float r3 = fmaxf(zT[i * 4 + 3] - tau, 0.f);
            a0s += r0; a1s += r1; a2s += r2; a3s += r3;
            b0s = fmaf(r0, r0, b0s); b1s = fmaf(r1, r1, b1s);
            b2s = fmaf(r2, r2, b2s); b3s = fmaf(r3, r3, b3s);
        }
        float s1 = (a0s + a1s) + (a2s + a3s);
        float s2 = (b0s + b1s) + (b2s + b3s);
        #pragma unroll
        for (int s = 1; s < 16; s <<= 1) {
            s1 += __shfl_xor(s1, s, 64);
            s2 += __shfl_xor(s2, s, 64);
        }
        tau += (s2 - 1.0f) * 0.5f * __builtin_amdgcn_rcpf(s1);
    }

    #pragma unroll
    for (int ci = 0; ci < 4; ci++)
        #pragma unroll
        for (int i = 0; i < 4; i++) {
            float r0 = fmaxf(zT[ci * 16 + i * 4 + 0] - tau, 0.f);
            float r1 = fmaxf(zT[ci * 16 + i * 4 + 1] - tau, 0.f);
            float r2 = fmaxf(zT[ci * 16 + i * 4 + 2] - tau, 0.f);
            float r3 = fmaxf(zT[ci * 16 + i * 4 + 3] - tau, 0.f);
            u32x2 pk = {packbf2(r0 * r0, r1 * r1), packbf2(r2 * r2, r3 * r3)};
            *(u32x2*)(P_lds + rown * 1032 + ci * 256 + i * 64 + l16 * 4) = pk;
        }
    __syncthreads();

    f32x4 oacc[4];
    #pragma unroll
    for (int nt = 0; nt < 4; nt++) oacc[nt] = (f32x4){0.f, 0.f, 0.f, 0.f};
    const short* vb0 = vt + (size_t)((bb * 8 + hh) * 64) * 1024;
    #pragma unroll
    for (int sup = 0; sup < 8; sup++) {
        bf16x8 pf = *(const bf16x8*)(P_lds + l16 * 1032 + sup * 128 + wv * 32 + quad * 8);
        #pragma unroll
        for (int nt = 0; nt < 4; nt++) {
            bf16x8 bv = *(const bf16x8*)(vb0 + (size_t)(nt * 16 + l16) * 1024
                                         + sup * 128 + wv * 32 + quad * 8);
            oacc[nt] = __builtin_amdgcn_mfma_f32_16x16x32_bf16(pf, bv, oacc[nt], 0, 0, 0);
        }
    }
    __syncthreads();

    #pragma unroll
    for (int nt = 0; nt < 4; nt++)
        #pragma unroll
        for (int rg = 0; rg < 4; rg++)
            osum[(wv * 16 + quad * 4 + rg) * 68 + nt * 16 + l16] = oacc[nt][rg];
    __syncthreads();
    #pragma unroll
    for (int i = 0; i < 2; i++) {
        int idx = t + 256 * i;
        int r = idx >> 5, dp = idx & 31;
        float e0 = 0.f, e1 = 0.f;
        #pragma unroll
        for (int w = 0; w < 4; w++) {
            e0 += osum[(w * 16 + r) * 68 + dp * 2];
            e1 += osum[(w * 16 + r) * 68 + dp * 2 + 1];
        }
        *(uint32_t*)(ohead + (size_t)(bb * 1024 + r0 + r) * 512 + hh * 64 + dp * 2) = packbf2(e0, e1);
    }
}

// ---------------------------------------------------------------------------
// Fused cooperative kernel: all 4 phases, grid-stride virtual units.
// ---------------------------------------------------------------------------
__global__ __launch_bounds__(256, 3) void fused_all(
        const float* __restrict__ x, const float* __restrict__ wqkv,
        const float* __restrict__ wout,
        short* __restrict__ xb, short* __restrict__ wqkvt, short* __restrict__ woutt,
        short* __restrict__ qkv_b, short* __restrict__ vt,
        short* __restrict__ ohead, float* __restrict__ out) {
    __shared__ __align__(16) unsigned char smem[33024];
    const int t = threadIdx.x;
    cg::grid_group grid = cg::this_grid();

    for (int u = blockIdx.x; u < 2048; u += gridDim.x)
        convert_unit(u, t, x, wqkv, wout, xb, wqkvt, woutt, smem);
    __threadfence();
    grid.sync();

    for (int u = blockIdx.x; u < 768; u += gridDim.x)
        gemm_tile<0>(xb, wqkvt, qkv_b, vt, nullptr, u / 12, u % 12, t, smem);
    __threadfence();
    grid.sync();

    for (int u = blockIdx.x; u < 2048; u += gridDim.x)
        attn_unit(u, t, qkv_b, vt, ohead, smem);
    __threadfence();
    grid.sync();

    for (int u = blockIdx.x; u < 256; u += gridDim.x)
        gemm_tile<1>(ohead, woutt, nullptr, nullptr, out, u >> 2, u & 3, t, smem);
}

// ---------------------------------------------------------------------------
// Fallback wrappers (regular launches) in case cooperative launch fails.
// ---------------------------------------------------------------------------
__global__ __launch_bounds__(256) void k_convert(const float* x, const float* wqkv,
        const float* wout, short* xb, short* wqkvt, short* woutt) {
    __shared__ __align__(16) unsigned char smem[4352];
    convert_unit(blockIdx.x, threadIdx.x, x, wqkv, wout, xb, wqkvt, woutt, smem);
}
__global__ __launch_bounds__(256) void k_gemm_qkv(const short* A, const short* Bt,
        short* qkv_b, short* vt) {
    __shared__ __align__(16) unsigned char smem[12288];
    gemm_tile<0>(A, Bt, qkv_b, vt, nullptr, blockIdx.x / 12, blockIdx.x % 12,
                 threadIdx.x, smem);
}
__global__ __launch_bounds__(256, 3) void k_attn(const short* qkv, const short* vt,
        short* ohead) {
    __shared__ __align__(16) unsigned char smem[33024];
    attn_unit(blockIdx.x, threadIdx.x, qkv, vt, ohead, smem);
}
__global__ __launch_bounds__(256) void k_gemm_out(const short* A, const short* Bt,
        float* out) {
    __shared__ __align__(16) unsigned char smem[12288];
    gemm_tile<1>(A, Bt, nullptr, nullptr, out, blockIdx.x >> 2, blockIdx.x & 3,
                 threadIdx.x, smem);
}

// ---------------------------------------------------------------------------
extern "C" void kernel_launch(void* const* d_in, const int* in_sizes, int n_in,
                              void* d_out, int out_size, void* d_ws, size_t ws_size,
                              hipStream_t stream) {
    (void)in_sizes; (void)n_in; (void)out_size; (void)ws_size;
    const float* x     = (const float*)d_in[0];
    const float* w_qkv = (const float*)d_in[1];
    const float* w_out = (const float*)d_in[2];
    float* out = (float*)d_out;

    char* ws = (char*)d_ws;
    short* qkv_b = (short*)(ws);                        // 8,388,608 B (Q|K)
    short* vt    = (short*)(ws + 8388608);              // 4,194,304 B (V^T)
    short* ohead = (short*)(ws + 12582912);             // 4,194,304 B
    short* xb    = (short*)(ws + 16777216);             // 4,194,304 B
    short* wqkvt = (short*)(ws + 20971520);             // 1,572,864 B
    short* woutt = (short*)(ws + 22544384);             //   524,288 B

    int nb = 0;
    hipError_t qe = hipOccupancyMaxActiveBlocksPerMultiprocessor(&nb, fused_all, 256, 0);
    if (qe == hipSuccess && nb >= 1) {
        int grid = nb * 256;
        if (grid > 1024) grid = 1024;
        void* args[] = {(void*)&x, (void*)&w_qkv, (void*)&w_out,
                        (void*)&xb, (void*)&wqkvt, (void*)&woutt,
                        (void*)&qkv_b, (void*)&vt, (void*)&ohead, (void*)&out};
        hipError_t le = hipLaunchCooperativeKernel((const void*)fused_all,
                                                   dim3(grid), dim3(256), args, 0, stream);
        if (le == hipSuccess) return;
    }
    // Fallback: 4 regular launches (identical math)
    k_convert<<<dim3(2048), dim3(256), 0, stream>>>(x, w_qkv, w_out, xb, wqkvt, woutt);
    k_gemm_qkv<<<dim3(768), dim3(256), 0, stream>>>(xb, wqkvt, qkv_b, vt);
    k_attn<<<dim3(2048), dim3(256), 0, stream>>>(qkv_b, vt, ohead);
    k_gemm_out<<<dim3(256), dim3(256), 0, stream>>>(ohead, woutt, out);
}

// Round 9
// 164.216 us; speedup vs baseline: 2.4512x; 2.4512x over previous
//
#include <hip/hip_runtime.h>
#include <stdint.h>
#include <stddef.h>

// b=4, n=1024, dim=512, heads=8, dh=64. qkv ws: [4096][1024] bf16 = Q|K only,
// q pre-scaled by 1/16; V transposed to vt[b][h][64][1024] bf16.

typedef __attribute__((ext_vector_type(4))) float f32x4;
typedef __attribute__((ext_vector_type(8))) short bf16x8;
typedef __attribute__((ext_vector_type(4))) uint32_t u32x4;
typedef __attribute__((ext_vector_type(2))) uint32_t u32x2;

__device__ inline unsigned short f2bf(float f) {
    union { float f; uint32_t u; } cv; cv.f = f;
    uint32_t u = cv.u;
    return (unsigned short)((u + 0x7fffu + ((u >> 16) & 1u)) >> 16);
}
__device__ inline uint32_t packbf2(float lo, float hi) {
    return (uint32_t)f2bf(lo) | ((uint32_t)f2bf(hi) << 16);
}
__device__ inline void gl_lds16(const short* g, short* l) {
    __builtin_amdgcn_global_load_lds(
        (const __attribute__((address_space(1))) void*)g,
        (__attribute__((address_space(3))) void*)l, 16, 0, 0);
}

// ---------------------------------------------------------------------------
// convert: x fp32 -> bf16; w_qkv [512][1536] -> wqkvt [1536][512] bf16 (T);
//          w_out [512][512] -> woutt [512][512] bf16 (T)
// ---------------------------------------------------------------------------
__global__ __launch_bounds__(256) void convert_all(const float* __restrict__ x,
                                                   const float* __restrict__ wqkv,
                                                   const float* __restrict__ wout,
                                                   short* __restrict__ xb,
                                                   short* __restrict__ wqkvt,
                                                   short* __restrict__ woutt) {
    __shared__ float tl[32][33];
    const int bid = blockIdx.x;
    const int t = threadIdx.x;
    if (bid < 1024) {
        int base = bid * 2048 + t * 8;
        f32x4 v0 = *(const f32x4*)(x + base);
        f32x4 v1 = *(const f32x4*)(x + base + 4);
        u32x4 o = {packbf2(v0[0], v0[1]), packbf2(v0[2], v0[3]),
                   packbf2(v1[0], v1[1]), packbf2(v1[2], v1[3])};
        *(u32x4*)(xb + base) = o;
        return;
    }
    const float* src; short* dst; int NC, tn, tk;
    if (bid < 1024 + 768) {
        int idx = bid - 1024; tn = idx % 48; tk = idx / 48; src = wqkv; dst = wqkvt; NC = 1536;
    } else {
        int idx = bid - 1792; tn = idx % 16; tk = idx / 16; src = wout; dst = woutt; NC = 512;
    }
    const int row = t >> 3, c4 = (t & 7) * 4;
    f32x4 v = *(const f32x4*)(src + (size_t)(tk * 32 + row) * NC + tn * 32 + c4);
    tl[row][c4 + 0] = v[0]; tl[row][c4 + 1] = v[1];
    tl[row][c4 + 2] = v[2]; tl[row][c4 + 3] = v[3];
    __syncthreads();
    float a = tl[c4 + 0][row], b = tl[c4 + 1][row];
    float c = tl[c4 + 2][row], d = tl[c4 + 3][row];
    u32x2 o = {packbf2(a, b), packbf2(c, d)};
    *(u32x2*)(dst + (size_t)(tn * 32 + row) * 512 + tk * 32 + c4) = o;
}

// ---------------------------------------------------------------------------
// gemm_qkv: m97-style 128x128 tile, BK=32, 256 thr. Grid 32 x 12.
// bn<4: q (*1/16) -> qkv_b cols 0..511; bn 4..7: k -> 512..1023;
// bn>=8: v -> vt[b][h][d][j] transposed bf16.
// ---------------------------------------------------------------------------
__global__ __launch_bounds__(256) void gemm_qkv(const short* __restrict__ A,
                                                const short* __restrict__ Bt,
                                                short* __restrict__ qkv_b,
                                                short* __restrict__ vt) {
    __shared__ __align__(16) short As[128 * 32];
    __shared__ __align__(16) short Bs[128 * 32];
    const int t = threadIdx.x;
    const int lane = t & 63;
    const int wv = t >> 6;
    const int quad = lane >> 4;
    const int l16 = lane & 15;
    const int bm = blockIdx.x / 12;
    const int bn = blockIdx.x % 12;
    const int wm = (wv & 1) * 64, wn = (wv >> 1) * 64;

    f32x4 acc[4][4];
    #pragma unroll
    for (int i = 0; i < 4; i++)
        #pragma unroll
        for (int j = 0; j < 4; j++) acc[i][j] = (f32x4){0.f, 0.f, 0.f, 0.f};

    const int srow = lane >> 2;
    const int scol = (lane & 3) * 8;

    for (int kt = 0; kt < 16; kt++) {
        #pragma unroll
        for (int cc = 0; cc < 2; cc++) {
            int chunk = wv + cc * 4;
            gl_lds16(A + (size_t)(bm * 128 + chunk * 16 + srow) * 512 + kt * 32 + scol,
                     As + chunk * 512);
            gl_lds16(Bt + (size_t)(bn * 128 + chunk * 16 + srow) * 512 + kt * 32 + scol,
                     Bs + chunk * 512);
        }
        __syncthreads();
        bf16x8 af[4], bfr[4];
        #pragma unroll
        for (int mi = 0; mi < 4; mi++)
            af[mi] = *(const bf16x8*)(As + (wm + mi * 16 + l16) * 32 + quad * 8);
        #pragma unroll
        for (int ni = 0; ni < 4; ni++)
            bfr[ni] = *(const bf16x8*)(Bs + (wn + ni * 16 + l16) * 32 + quad * 8);
        #pragma unroll
        for (int mi = 0; mi < 4; mi++)
            #pragma unroll
            for (int ni = 0; ni < 4; ni++)
                acc[mi][ni] = __builtin_amdgcn_mfma_f32_16x16x32_bf16(af[mi], bfr[ni], acc[mi][ni], 0, 0, 0);
        __syncthreads();
    }

    if (bn < 8) {
        const float scq = (bn < 4) ? 0.0625f : 1.0f;
        #pragma unroll
        for (int mi = 0; mi < 4; mi++)
            #pragma unroll
            for (int ni = 0; ni < 4; ni++)
                #pragma unroll
                for (int rg = 0; rg < 4; rg++)
                    qkv_b[(size_t)(bm * 128 + wm + mi * 16 + quad * 4 + rg) * 1024
                          + bn * 128 + wn + ni * 16 + l16] = (short)f2bf(acc[mi][ni][rg] * scq);
    } else {
        #pragma unroll
        for (int mi = 0; mi < 4; mi++) {
            int rowb = bm * 128 + wm + mi * 16 + quad * 4;
            int bbb = rowb >> 10, j = rowb & 1023;
            #pragma unroll
            for (int ni = 0; ni < 4; ni++) {
                int vcol = bn * 128 + wn + ni * 16 + l16 - 1024;
                int hh = vcol >> 6, dd = vcol & 63;
                u32x2 pk = {packbf2(acc[mi][ni][0], acc[mi][ni][1]),
                            packbf2(acc[mi][ni][2], acc[mi][ni][3])};
                *(u32x2*)(vt + ((size_t)((bbb * 8 + hh) * 64 + dd)) * 1024 + j) = pk;
            }
        }
    }
}

// ---------------------------------------------------------------------------
// gemm_out: 64m x 128n tile, BK=64, grid 256 (1 CU round).
// ---------------------------------------------------------------------------
__global__ __launch_bounds__(256) void gemm_out(const short* __restrict__ A,
                                                const short* __restrict__ Bt,
                                                float* __restrict__ of) {
    __shared__ __align__(16) short As[64 * 64];
    __shared__ __align__(16) short Bs[128 * 64];
    const int t = threadIdx.x;
    const int lane = t & 63;
    const int wv = t >> 6;
    const int quad = lane >> 4;
    const int l16 = lane & 15;
    const int bm = blockIdx.x >> 2;
    const int bn = blockIdx.x & 3;
    const int wm = (wv & 1) * 32, wn = (wv >> 1) * 64;

    f32x4 acc[2][4];
    #pragma unroll
    for (int i = 0; i < 2; i++)
        #pragma unroll
        for (int j = 0; j < 4; j++) acc[i][j] = (f32x4){0.f, 0.f, 0.f, 0.f};

    const int sr = t >> 3, sc = (t & 7) * 8;

    for (int kt = 0; kt < 8; kt++) {
        #pragma unroll
        for (int h = 0; h < 2; h++)
            gl_lds16(A + (size_t)(bm * 64 + h * 32 + sr) * 512 + kt * 64 + sc,
                     As + (h * 32 + sr) * 64 + sc);
        #pragma unroll
        for (int h = 0; h < 4; h++)
            gl_lds16(Bt + (size_t)(bn * 128 + h * 32 + sr) * 512 + kt * 64 + sc,
                     Bs + (h * 32 + sr) * 64 + sc);
        __syncthreads();
        bf16x8 af[2][2], bfr[4][2];
        #pragma unroll
        for (int mi = 0; mi < 2; mi++)
            #pragma unroll
            for (int kh = 0; kh < 2; kh++)
                af[mi][kh] = *(const bf16x8*)(As + (wm + mi * 16 + l16) * 64 + kh * 32 + quad * 8);
        #pragma unroll
        for (int ni = 0; ni < 4; ni++)
            #pragma unroll
            for (int kh = 0; kh < 2; kh++)
                bfr[ni][kh] = *(const bf16x8*)(Bs + (wn + ni * 16 + l16) * 64 + kh * 32 + quad * 8);
        #pragma unroll
        for (int kh = 0; kh < 2; kh++)
            #pragma unroll
            for (int mi = 0; mi < 2; mi++)
                #pragma unroll
                for (int ni = 0; ni < 4; ni++)
                    acc[mi][ni] = __builtin_amdgcn_mfma_f32_16x16x32_bf16(af[mi][kh], bfr[ni][kh], acc[mi][ni], 0, 0, 0);
        __syncthreads();
    }
    #pragma unroll
    for (int mi = 0; mi < 2; mi++)
        #pragma unroll
        for (int ni = 0; ni < 4; ni++)
            #pragma unroll
            for (int rg = 0; rg < 4; rg++)
                of[(size_t)(bm * 64 + wm + mi * 16 + quad * 4 + rg) * 512
                   + bn * 128 + wn + ni * 16 + l16] = acc[mi][ni][rg];
}

// ---------------------------------------------------------------------------
// Fused entmax-1.5 attention: 32 query rows/block, 512 threads (8 waves),
// 1024 blocks. Wave w: rh = w&1 (row-half), jg = w>>1 (col-quarter).
// Scores in 4 column-chunks -> LDS transpose -> thread t owns all 1024 j of
// row t>>4 (64 regs). Barrier-free Newton (16-lane groups). PV in two j-half
// passes (P_half 32x524 bf16 in LDS; oacc persists across passes).
// K/V L2 traffic halves vs 16-row blocks.
// ---------------------------------------------------------------------------
__global__ __launch_bounds__(512, 4) void attn_entmax(const short* __restrict__ qkv,
                                                      const short* __restrict__ vt,
                                                      short* __restrict__ oheads) {
    __shared__ __align__(16) unsigned char smem[34304];
    float* tbuf = (float*)smem;             // [32][268] fp32 (transpose phase)
    short* P_lds = (short*)smem;            // [32][524] bf16 (PV passes) 33536 B
    float* osum = (float*)smem;             // [(row*4+jq)*67 + d] (after PV)

    const int t = threadIdx.x;
    const int lane = t & 63;
    const int wv = t >> 6;                  // 0..7
    const int quad = lane >> 4;
    const int l16 = lane & 15;
    const int rh = wv & 1;                  // row-half
    const int jg = wv >> 1;                 // col-quarter

    const int xcd = blockIdx.x & 7;
    const int g = blockIdx.x >> 3;          // 0..127
    const int hb = xcd * 4 + (g >> 5);      // 0..31
    const int rt = g & 31;
    const int bb = hb >> 3, hh = hb & 7;
    const int r0 = rt * 32;

    // Q A-frags for this wave's 16-row half
    bf16x8 a0, a1;
    {
        const short* qp = qkv + (size_t)(bb * 1024 + r0 + rh * 16 + l16) * 1024 + hh * 64 + quad * 8;
        a0 = *(const bf16x8*)qp;
        a1 = *(const bf16x8*)(qp + 32);
    }

    // ---- scores in 4 column-chunks of 64 per wave, transposed to row-owner ----
    // zT[(4*jg2+ci)*4 + c] = z[row t>>4][col (4*jg2+ci)*64 + (t&15)*4 + c]
    float zT[64];
    const short* kb0 = qkv + (size_t)(bb * 1024) * 1024 + 512 + hh * 64 + quad * 8;
    const int rown = t >> 4;                // owned row 0..31
    const int dg = t & 15;
    for (int ci = 0; ci < 4; ci++) {
        f32x4 zc[4];
        #pragma unroll
        for (int ct = 0; ct < 4; ct++) {
            int j0 = jg * 256 + ci * 64 + ct * 16 + l16;
            const short* kp = kb0 + (size_t)j0 * 1024;
            bf16x8 b0 = *(const bf16x8*)kp;
            bf16x8 b1 = *(const bf16x8*)(kp + 32);
            f32x4 acc = {0.f, 0.f, 0.f, 0.f};
            acc = __builtin_amdgcn_mfma_f32_16x16x32_bf16(a0, b0, acc, 0, 0, 0);
            acc = __builtin_amdgcn_mfma_f32_16x16x32_bf16(a1, b1, acc, 0, 0, 0);
            zc[ct] = acc;
        }
        __syncthreads();                    // previous chunk's readback done
        #pragma unroll
        for (int ct = 0; ct < 4; ct++)
            #pragma unroll
            for (int rg = 0; rg < 4; rg++)
                tbuf[(rh * 16 + quad * 4 + rg) * 268 + jg * 64 + ct * 16 + l16] = zc[ct][rg];
        __syncthreads();
        #pragma unroll
        for (int jg2 = 0; jg2 < 4; jg2++) {
            f32x4 v = *(const f32x4*)(tbuf + rown * 268 + jg2 * 64 + dg * 4);
            int i = jg2 * 4 + ci;
            zT[i * 4 + 0] = v[0]; zT[i * 4 + 1] = v[1];
            zT[i * 4 + 2] = v[2]; zT[i * 4 + 3] = v[3];
        }
    }
    __syncthreads();                        // last readback done; smem reusable

    // ---- init: rowmax + full-support closed-form tau, clamped to bracket ----
    float tau;
    {
        float m0 = zT[0], m1 = zT[1], m2 = zT[2], m3 = zT[3];
        float p0 = zT[0], p1 = zT[1], p2 = zT[2], p3 = zT[3];
        float q0 = zT[0] * zT[0], q1 = zT[1] * zT[1], q2 = zT[2] * zT[2], q3 = zT[3] * zT[3];
        #pragma unroll
        for (int i = 1; i < 16; i++) {
            float v0 = zT[i * 4], v1 = zT[i * 4 + 1], v2 = zT[i * 4 + 2], v3 = zT[i * 4 + 3];
            m0 = fmaxf(m0, v0); m1 = fmaxf(m1, v1); m2 = fmaxf(m2, v2); m3 = fmaxf(m3, v3);
            p0 += v0; p1 += v1; p2 += v2; p3 += v3;
            q0 = fmaf(v0, v0, q0); q1 = fmaf(v1, v1, q1);
            q2 = fmaf(v2, v2, q2); q3 = fmaf(v3, v3, q3);
        }
        float mx = fmaxf(fmaxf(m0, m1), fmaxf(m2, m3));
        float s1 = (p0 + p1) + (p2 + p3);
        float s2 = (q0 + q1) + (q2 + q3);
        #pragma unroll
        for (int s = 1; s < 16; s <<= 1) {
            mx = fmaxf(mx, __shfl_xor(mx, s, 64));
            s1 += __shfl_xor(s1, s, 64);
            s2 += __shfl_xor(s2, s, 64);
        }
        float mean = s1 * (1.0f / 1024.0f);
        float disc = fmaxf(mean * mean - (s2 - 1.0f) * (1.0f / 1024.0f), 0.0f);
        tau = mean - __builtin_sqrtf(disc);
        tau = fminf(tau, mx - 0.03125f);    // tau* <= mx - 1/sqrt(n)
        tau = fmaxf(tau, mx - 1.0f);        // tau* >= mx - 1
    }

    // ---- Newton (barrier-free): f(tau)=sum relu(z-tau)^2 - 1, convex ----
    for (int it = 0; it < 8; it++) {
        float a0s = 0.f, a1s = 0.f, a2s = 0.f, a3s = 0.f;
        float b0s = 0.f, b1s = 0.f, b2s = 0.f, b3s = 0.f;
        #pragma unroll
        for (int i = 0; i < 16; i++) {
            float r0 = fmaxf(zT[i * 4] - tau, 0.f);
            float r1 = fmaxf(zT[i * 4 + 1] - tau, 0.f);
            float r2 = fmaxf(zT[i * 4 + 2] - tau, 0.f);
            float r3 = fmaxf(zT[i * 4 + 3] - tau, 0.f);
            a0s += r0; a1s += r1; a2s += r2; a3s += r3;
            b0s = fmaf(r0, r0, b0s); b1s = fmaf(r1, r1, b1s);
            b2s = fmaf(r2, r2, b2s); b3s = fmaf(r3, r3, b3s);
        }
        float s1 = (a0s + a1s) + (a2s + a3s);
        float s2 = (b0s + b1s) + (b2s + b3s);
        #pragma unroll
        for (int s = 1; s < 16; s <<= 1) {
            s1 += __shfl_xor(s1, s, 64);
            s2 += __shfl_xor(s2, s, 64);
        }
        tau += (s2 - 1.0f) * 0.5f * __builtin_amdgcn_rcpf(s1);
    }

    // ---- PV in two j-half passes: P_half[32][524] bf16 ----
    f32x4 oacc[4];
    #pragma unroll
    for (int nt = 0; nt < 4; nt++) oacc[nt] = (f32x4){0.f, 0.f, 0.f, 0.f};
    const short* vb0 = vt + (size_t)((bb * 8 + hh) * 64) * 1024;
    for (int jh = 0; jh < 2; jh++) {
        __syncthreads();                    // previous pass P reads done
        #pragma unroll
        for (int ii = 0; ii < 8; ii++) {
            int i = jh * 8 + ii;
            float r0 = fmaxf(zT[i * 4 + 0] - tau, 0.f);
            float r1 = fmaxf(zT[i * 4 + 1] - tau, 0.f);
            float r2 = fmaxf(zT[i * 4 + 2] - tau, 0.f);
            float r3 = fmaxf(zT[i * 4 + 3] - tau, 0.f);
            u32x2 pk = {packbf2(r0 * r0, r1 * r1), packbf2(r2 * r2, r3 * r3)};
            *(u32x2*)(P_lds + rown * 524 + ii * 64 + dg * 4) = pk;
        }
        __syncthreads();
        // wave (rh, jg): rows rh*16..+16, j = jh*512 + jg*128 + sup*32 + quad*8
        #pragma unroll
        for (int sup = 0; sup < 4; sup++) {
            bf16x8 pf = *(const bf16x8*)(P_lds + (rh * 16 + l16) * 524
                                         + jg * 128 + sup * 32 + quad * 8);
            #pragma unroll
            for (int nt = 0; nt < 4; nt++) {
                bf16x8 bv = *(const bf16x8*)(vb0 + (size_t)(nt * 16 + l16) * 1024
                                             + jh * 512 + jg * 128 + sup * 32 + quad * 8);
                oacc[nt] = __builtin_amdgcn_mfma_f32_16x16x32_bf16(pf, bv, oacc[nt], 0, 0, 0);
            }
        }
    }
    __syncthreads();                        // P dead; overlay osum

    // osum[(row*4 + jq)*67 + d], row 0..31, jq = jg, d = nt*16+l16
    #pragma unroll
    for (int nt = 0; nt < 4; nt++)
        #pragma unroll
        for (int rg = 0; rg < 4; rg++)
            osum[((rh * 16 + quad * 4 + rg) * 4 + jg) * 67 + nt * 16 + l16] = oacc[nt][rg];
    __syncthreads();
    #pragma unroll
    for (int i = 0; i < 2; i++) {
        int idx = t + 512 * i;              // 1024 col-pair tasks (32 rows x 32 dp)
        int r = idx >> 5, dp = idx & 31;
        float e0 = 0.f, e1 = 0.f;
        #pragma unroll
        for (int jq = 0; jq < 4; jq++) {
            e0 += osum[(r * 4 + jq) * 67 + dp * 2];
            e1 += osum[(r * 4 + jq) * 67 + dp * 2 + 1];
        }
        *(uint32_t*)(oheads + (size_t)(bb * 1024 + r0 + r) * 512 + hh * 64 + dp * 2) = packbf2(e0, e1);
    }
}

// ---------------------------------------------------------------------------
extern "C" void kernel_launch(void* const* d_in, const int* in_sizes, int n_in,
                              void* d_out, int out_size, void* d_ws, size_t ws_size,
                              hipStream_t stream) {
    (void)in_sizes; (void)n_in; (void)out_size; (void)ws_size;
    const float* x     = (const float*)d_in[0];
    const float* w_qkv = (const float*)d_in[1];
    const float* w_out = (const float*)d_in[2];
    float* out = (float*)d_out;

    char* ws = (char*)d_ws;
    short* qkv_b = (short*)(ws);                        // 8,388,608 B (Q|K)
    short* vt    = (short*)(ws + 8388608);              // 4,194,304 B (V^T)
    short* ohead = (short*)(ws + 12582912);             // 4,194,304 B
    short* xb    = (short*)(ws + 16777216);             // 4,194,304 B
    short* wqkvt = (short*)(ws + 20971520);             // 1,572,864 B
    short* woutt = (short*)(ws + 22544384);             //   524,288 B

    convert_all<<<dim3(2048), dim3(256), 0, stream>>>(x, w_qkv, w_out, xb, wqkvt, woutt);
    gemm_qkv<<<dim3(32 * 12), dim3(256), 0, stream>>>(xb, wqkvt, qkv_b, vt);
    attn_entmax<<<dim3(1024), dim3(512), 0, stream>>>(qkv_b, vt, ohead);
    gemm_out<<<dim3(256), dim3(256), 0, stream>>>(ohead, woutt, out);
}

// Round 10
// 151.851 us; speedup vs baseline: 2.6508x; 1.0814x over previous
//
#include <hip/hip_runtime.h>
#include <stdint.h>
#include <stddef.h>

// b=4, n=1024, dim=512, heads=8, dh=64. qkv ws: [4096][1024] bf16 = Q|K only,
// q pre-scaled by 1/16; V transposed to vt[b][h][64][1024] bf16.

typedef __attribute__((ext_vector_type(4))) float f32x4;
typedef __attribute__((ext_vector_type(2))) float f32x2;
typedef __attribute__((ext_vector_type(8))) short bf16x8;
typedef __attribute__((ext_vector_type(4))) uint32_t u32x4;
typedef __attribute__((ext_vector_type(2))) uint32_t u32x2;

__device__ inline unsigned short f2bf(float f) {
    union { float f; uint32_t u; } cv; cv.f = f;
    uint32_t u = cv.u;
    return (unsigned short)((u + 0x7fffu + ((u >> 16) & 1u)) >> 16);
}
__device__ inline uint32_t packbf2(float lo, float hi) {
    return (uint32_t)f2bf(lo) | ((uint32_t)f2bf(hi) << 16);
}
__device__ inline void gl_lds16(const short* g, short* l) {
    __builtin_amdgcn_global_load_lds(
        (const __attribute__((address_space(1))) void*)g,
        (__attribute__((address_space(3))) void*)l, 16, 0, 0);
}
// packed-fp32 helpers -> v_pk_max_f32 / v_pk_fma_f32
__device__ inline f32x2 vmax2(f32x2 a, f32x2 b) { return __builtin_elementwise_max(a, b); }
__device__ inline f32x2 vfma2(f32x2 a, f32x2 b, f32x2 c) { return __builtin_elementwise_fma(a, b, c); }

// ---------------------------------------------------------------------------
// convert: x fp32 -> bf16; w_qkv [512][1536] -> wqkvt [1536][512] bf16 (T);
//          w_out [512][512] -> woutt [512][512] bf16 (T)
// ---------------------------------------------------------------------------
__global__ __launch_bounds__(256) void convert_all(const float* __restrict__ x,
                                                   const float* __restrict__ wqkv,
                                                   const float* __restrict__ wout,
                                                   short* __restrict__ xb,
                                                   short* __restrict__ wqkvt,
                                                   short* __restrict__ woutt) {
    __shared__ float tl[32][33];
    const int bid = blockIdx.x;
    const int t = threadIdx.x;
    if (bid < 1024) {
        int base = bid * 2048 + t * 8;
        f32x4 v0 = *(const f32x4*)(x + base);
        f32x4 v1 = *(const f32x4*)(x + base + 4);
        u32x4 o = {packbf2(v0[0], v0[1]), packbf2(v0[2], v0[3]),
                   packbf2(v1[0], v1[1]), packbf2(v1[2], v1[3])};
        *(u32x4*)(xb + base) = o;
        return;
    }
    const float* src; short* dst; int NC, tn, tk;
    if (bid < 1024 + 768) {
        int idx = bid - 1024; tn = idx % 48; tk = idx / 48; src = wqkv; dst = wqkvt; NC = 1536;
    } else {
        int idx = bid - 1792; tn = idx % 16; tk = idx / 16; src = wout; dst = woutt; NC = 512;
    }
    const int row = t >> 3, c4 = (t & 7) * 4;
    f32x4 v = *(const f32x4*)(src + (size_t)(tk * 32 + row) * NC + tn * 32 + c4);
    tl[row][c4 + 0] = v[0]; tl[row][c4 + 1] = v[1];
    tl[row][c4 + 2] = v[2]; tl[row][c4 + 3] = v[3];
    __syncthreads();
    float a = tl[c4 + 0][row], b = tl[c4 + 1][row];
    float c = tl[c4 + 2][row], d = tl[c4 + 3][row];
    u32x2 o = {packbf2(a, b), packbf2(c, d)};
    *(u32x2*)(dst + (size_t)(tn * 32 + row) * 512 + tk * 32 + c4) = o;
}

// ---------------------------------------------------------------------------
// bf16 MFMA GEMM: 64m x 128n tile, 256 thr (4 waves of 32x64), BK=32 (r3 cfg).
// MODE 0: qkv_b [M][1024] (bn<4: q*1/16; bn 4..7: k) + vt scatter (bn>=8).
// MODE 1: fp32 [M][512].
// ---------------------------------------------------------------------------
template<int NB, int MODE>
__global__ __launch_bounds__(256) void gemm_bf16(const short* __restrict__ A,
                                                 const short* __restrict__ Bt,
                                                 void* __restrict__ outp,
                                                 short* __restrict__ vt) {
    __shared__ __align__(16) short As[64 * 32];
    __shared__ __align__(16) short Bs[128 * 32];
    const int t = threadIdx.x;
    const int lane = t & 63;
    const int wv = t >> 6;
    const int quad = lane >> 4;
    const int l16 = lane & 15;
    const int bm = blockIdx.x / NB;
    const int bn = blockIdx.x % NB;
    const int wm = (wv & 1) * 32, wn = (wv >> 1) * 64;

    f32x4 acc[2][4];
    #pragma unroll
    for (int i = 0; i < 2; i++)
        #pragma unroll
        for (int j = 0; j < 4; j++) acc[i][j] = (f32x4){0.f, 0.f, 0.f, 0.f};

    const int sr = t >> 2, sc = (t & 3) * 8;

    for (int kt = 0; kt < 16; kt++) {
        gl_lds16(A + (size_t)(bm * 64 + sr) * 512 + kt * 32 + sc, As + t * 8);
        #pragma unroll
        for (int i = 0; i < 2; i++)
            gl_lds16(Bt + (size_t)(bn * 128 + 64 * i + sr) * 512 + kt * 32 + sc,
                     Bs + 64 * i * 32 + t * 8);
        __syncthreads();
        bf16x8 af[2], bfr[4];
        #pragma unroll
        for (int mi = 0; mi < 2; mi++)
            af[mi] = *(const bf16x8*)(As + (wm + mi * 16 + l16) * 32 + quad * 8);
        #pragma unroll
        for (int ni = 0; ni < 4; ni++)
            bfr[ni] = *(const bf16x8*)(Bs + (wn + ni * 16 + l16) * 32 + quad * 8);
        #pragma unroll
        for (int mi = 0; mi < 2; mi++)
            #pragma unroll
            for (int ni = 0; ni < 4; ni++)
                acc[mi][ni] = __builtin_amdgcn_mfma_f32_16x16x32_bf16(af[mi], bfr[ni], acc[mi][ni], 0, 0, 0);
        __syncthreads();
    }

    if (MODE == 0) {
        short* ob = (short*)outp;
        if (bn < 8) {
            const float scq = (bn < 4) ? 0.0625f : 1.0f;
            #pragma unroll
            for (int mi = 0; mi < 2; mi++)
                #pragma unroll
                for (int ni = 0; ni < 4; ni++)
                    #pragma unroll
                    for (int rg = 0; rg < 4; rg++)
                        ob[(size_t)(bm * 64 + wm + mi * 16 + quad * 4 + rg) * 1024
                           + bn * 128 + wn + ni * 16 + l16] = (short)f2bf(acc[mi][ni][rg] * scq);
        } else {
            #pragma unroll
            for (int mi = 0; mi < 2; mi++) {
                int rowb = bm * 64 + wm + mi * 16 + quad * 4;
                int bbb = rowb >> 10, j = rowb & 1023;
                #pragma unroll
                for (int ni = 0; ni < 4; ni++) {
                    int vcol = bn * 128 + wn + ni * 16 + l16 - 1024;   // 0..511
                    int hh = vcol >> 6, dd = vcol & 63;
                    u32x2 pk = {packbf2(acc[mi][ni][0], acc[mi][ni][1]),
                                packbf2(acc[mi][ni][2], acc[mi][ni][3])};
                    *(u32x2*)(vt + ((size_t)((bbb * 8 + hh) * 64 + dd)) * 1024 + j) = pk;
                }
            }
        }
    } else {
        float* of = (float*)outp;
        #pragma unroll
        for (int mi = 0; mi < 2; mi++)
            #pragma unroll
            for (int ni = 0; ni < 4; ni++)
                #pragma unroll
                for (int rg = 0; rg < 4; rg++)
                    of[(size_t)(bm * 64 + wm + mi * 16 + quad * 4 + rg) * 512
                       + bn * 128 + wn + ni * 16 + l16] = acc[mi][ni][rg];
    }
}

// ---------------------------------------------------------------------------
// Fused entmax-1.5 attention (r6 structure): 16 query rows/block, 256 thr.
// Scores in 4 column-chunks -> LDS transpose to row-owner regs (no spill).
// Newton barrier-free with packed-fp32 (v_pk_*) math, 7 iters.
// P stored in 32 KB XOR-swizzled LDS (exactly 32768 B -> 5 blocks/CU).
// ---------------------------------------------------------------------------
__global__ __launch_bounds__(256, 5) void attn_entmax(const short* __restrict__ qkv,
                                                      const short* __restrict__ vt,
                                                      short* __restrict__ oheads) {
    __shared__ __align__(16) unsigned char smem[32768];
    short* P_lds = (short*)smem;            // [16][1024] bf16, XOR-swizzled 8-blocks
    float* tbuf = (float*)smem;             // [16][268] fp32 transpose buf (17152 B)
    float* osum = (float*)smem;             // [16][68] fp32 (4352 B)

    const int t = threadIdx.x;
    const int lane = t & 63;
    const int wv = t >> 6;
    const int quad = lane >> 4;
    const int l16 = lane & 15;

    const int xcd = blockIdx.x & 7;
    const int g = blockIdx.x >> 3;
    const int hb = xcd * 4 + (g >> 6);      // 0..31
    const int rt = g & 63;
    const int bb = hb >> 3, hh = hb & 7;
    const int r0 = rt * 16;

    // Q A-frags (16 real rows); q pre-scaled by 1/16 so z = sim/2 directly
    bf16x8 a0, a1;
    {
        const short* qp = qkv + (size_t)(bb * 1024 + r0 + l16) * 1024 + hh * 64 + quad * 8;
        a0 = *(const bf16x8*)qp;
        a1 = *(const bf16x8*)(qp + 32);
    }

    // ---- scores in 4 column-chunks of 256, transposed to row-owner layout ----
    // zT2[ci*8 + i*2 + (c>>1)][c&1] = z[row quad*4+wv][col ci*256 + i*64 + l16*4 + c]
    f32x2 zT2[32];
    const short* kb0 = qkv + (size_t)(bb * 1024) * 1024 + 512 + hh * 64 + quad * 8;
    const int rown = quad * 4 + wv;         // owned row
    for (int ci = 0; ci < 4; ci++) {
        f32x4 zc[4];
        #pragma unroll
        for (int f = 0; f < 4; f++) {
            int supl = f >> 1, jj = f & 1;
            int j0 = (ci * 2 + supl) * 128 + (wv + 4 * jj) * 16 + l16;
            const short* kp = kb0 + (size_t)j0 * 1024;
            bf16x8 b0 = *(const bf16x8*)kp;
            bf16x8 b1 = *(const bf16x8*)(kp + 32);
            f32x4 acc = {0.f, 0.f, 0.f, 0.f};
            acc = __builtin_amdgcn_mfma_f32_16x16x32_bf16(a0, b0, acc, 0, 0, 0);
            acc = __builtin_amdgcn_mfma_f32_16x16x32_bf16(a1, b1, acc, 0, 0, 0);
            zc[f] = acc;
        }
        __syncthreads();                    // previous chunk's readback complete
        #pragma unroll
        for (int f = 0; f < 4; f++) {
            int supl = f >> 1, jj = f & 1;
            int colc = supl * 128 + (wv + 4 * jj) * 16 + l16;
            #pragma unroll
            for (int rg = 0; rg < 4; rg++)
                tbuf[(quad * 4 + rg) * 268 + colc] = zc[f][rg];
        }
        __syncthreads();
        #pragma unroll
        for (int i = 0; i < 4; i++) {
            f32x4 v = *(const f32x4*)(tbuf + rown * 268 + i * 64 + l16 * 4);
            zT2[ci * 8 + i * 2 + 0] = (f32x2){v[0], v[1]};
            zT2[ci * 8 + i * 2 + 1] = (f32x2){v[2], v[3]};
        }
    }
    __syncthreads();                        // last readback done; smem reusable

    // ---- init: mx + full-support closed-form tau, clamped to bracket ----
    float tau;
    {
        f32x2 m2 = zT2[0], p2 = zT2[0];
        f32x2 q2 = zT2[0] * zT2[0];
        #pragma unroll
        for (int i = 1; i < 32; i++) {
            f32x2 v = zT2[i];
            m2 = vmax2(m2, v);
            p2 = p2 + v;
            q2 = vfma2(v, v, q2);
        }
        float mx = fmaxf(m2[0], m2[1]);
        float s1 = p2[0] + p2[1];
        float s2 = q2[0] + q2[1];
        #pragma unroll
        for (int s = 1; s < 16; s <<= 1) {
            mx = fmaxf(mx, __shfl_xor(mx, s, 64));
            s1 += __shfl_xor(s1, s, 64);
            s2 += __shfl_xor(s2, s, 64);
        }
        float mean = s1 * (1.0f / 1024.0f);
        float disc = fmaxf(mean * mean - (s2 - 1.0f) * (1.0f / 1024.0f), 0.0f);
        tau = mean - __builtin_sqrtf(disc);
        tau = fminf(tau, mx - 0.03125f);    // tau* <= mx - 1/sqrt(n)
        tau = fmaxf(tau, mx - 1.0f);        // tau* >= mx - 1
    }

    // ---- Newton (barrier-free, packed fp32): f(tau)=sum relu(z-tau)^2 - 1 ----
    const f32x2 zero2 = {0.f, 0.f};
    for (int it = 0; it < 7; it++) {
        f32x2 tau2 = {tau, tau};
        f32x2 s1a = zero2, s1b = zero2, s2a = zero2, s2b = zero2;
        #pragma unroll
        for (int i = 0; i < 16; i++) {
            f32x2 ra = vmax2(zT2[i * 2] - tau2, zero2);
            f32x2 rb = vmax2(zT2[i * 2 + 1] - tau2, zero2);
            s1a = s1a + ra; s1b = s1b + rb;
            s2a = vfma2(ra, ra, s2a); s2b = vfma2(rb, rb, s2b);
        }
        float s1 = (s1a[0] + s1a[1]) + (s1b[0] + s1b[1]);
        float s2 = (s2a[0] + s2a[1]) + (s2b[0] + s2b[1]);
        #pragma unroll
        for (int s = 1; s < 16; s <<= 1) {
            s1 += __shfl_xor(s1, s, 64);
            s2 += __shfl_xor(s2, s, 64);
        }
        tau += (s2 - 1.0f) * 0.5f * __builtin_amdgcn_rcpf(s1);
    }

    // ---- P = relu(z-tau)^2 -> swizzled P_lds (bf16, A-operand layout) ----
    // off(row, j) = row*1024 + ((jb ^ (row&7))<<3) + (j&7), jb = j>>3
    {
        const f32x2 tau2 = {tau, tau};
        const int dg = l16;
        const int ra = rown & 7;
        #pragma unroll
        for (int ci = 0; ci < 4; ci++)
            #pragma unroll
            for (int i = 0; i < 4; i++) {
                f32x2 r01 = vmax2(zT2[ci * 8 + i * 2] - tau2, zero2);
                f32x2 r23 = vmax2(zT2[ci * 8 + i * 2 + 1] - tau2, zero2);
                f32x2 p01 = r01 * r01, p23 = r23 * r23;
                u32x2 pk = {packbf2(p01[0], p01[1]), packbf2(p23[0], p23[1])};
                int jb = ci * 32 + i * 8 + (dg >> 1);
                *(u32x2*)(P_lds + rown * 1024 + ((jb ^ ra) << 3) + (dg & 1) * 4) = pk;
            }
    }
    __syncthreads();

    // ---- PV from global V^T: O[r][d] += P[r][j] V[j][d] ----
    f32x4 oacc[4];
    #pragma unroll
    for (int nt = 0; nt < 4; nt++) oacc[nt] = (f32x4){0.f, 0.f, 0.f, 0.f};
    const short* vb0 = vt + (size_t)((bb * 8 + hh) * 64) * 1024;
    const int lra = l16 & 7;
    #pragma unroll
    for (int sup = 0; sup < 8; sup++) {
        int jb = sup * 16 + wv * 4 + quad;
        bf16x8 pf = *(const bf16x8*)(P_lds + l16 * 1024 + ((jb ^ lra) << 3));
        #pragma unroll
        for (int nt = 0; nt < 4; nt++) {
            bf16x8 bv = *(const bf16x8*)(vb0 + (size_t)(nt * 16 + l16) * 1024
                                         + sup * 128 + wv * 32 + quad * 8);
            oacc[nt] = __builtin_amdgcn_mfma_f32_16x16x32_bf16(pf, bv, oacc[nt], 0, 0, 0);
        }
    }
    __syncthreads();                        // all P reads done; overlay osum

    #pragma unroll
    for (int nt = 0; nt < 4; nt++)
        #pragma unroll
        for (int rg = 0; rg < 4; rg++)
            osum[(wv * 16 + quad * 4 + rg) * 68 + nt * 16 + l16] = oacc[nt][rg];
    __syncthreads();
    #pragma unroll
    for (int i = 0; i < 2; i++) {
        int idx = t + 256 * i;
        int r = idx >> 5, dp = idx & 31;
        float e0 = 0.f, e1 = 0.f;
        #pragma unroll
        for (int w = 0; w < 4; w++) {
            e0 += osum[(w * 16 + r) * 68 + dp * 2];
            e1 += osum[(w * 16 + r) * 68 + dp * 2 + 1];
        }
        *(uint32_t*)(oheads + (size_t)(bb * 1024 + r0 + r) * 512 + hh * 64 + dp * 2) = packbf2(e0, e1);
    }
}

// ---------------------------------------------------------------------------
extern "C" void kernel_launch(void* const* d_in, const int* in_sizes, int n_in,
                              void* d_out, int out_size, void* d_ws, size_t ws_size,
                              hipStream_t stream) {
    (void)in_sizes; (void)n_in; (void)out_size; (void)ws_size;
    const float* x     = (const float*)d_in[0];
    const float* w_qkv = (const float*)d_in[1];
    const float* w_out = (const float*)d_in[2];
    float* out = (float*)d_out;

    char* ws = (char*)d_ws;
    short* qkv_b = (short*)(ws);                        // 8,388,608 B (Q|K)
    short* vt    = (short*)(ws + 8388608);              // 4,194,304 B (V^T)
    short* ohead = (short*)(ws + 12582912);             // 4,194,304 B
    short* xb    = (short*)(ws + 16777216);             // 4,194,304 B
    short* wqkvt = (short*)(ws + 20971520);             // 1,572,864 B
    short* woutt = (short*)(ws + 22544384);             //   524,288 B

    convert_all<<<dim3(2048), dim3(256), 0, stream>>>(x, w_qkv, w_out, xb, wqkvt, woutt);
    gemm_bf16<12, 0><<<dim3(64 * 12), dim3(256), 0, stream>>>(xb, wqkvt, (void*)qkv_b, vt);
    attn_entmax<<<dim3(2048), dim3(256), 0, stream>>>(qkv_b, vt, ohead);
    gemm_bf16<4, 1><<<dim3(64 * 4), dim3(256), 0, stream>>>(ohead, woutt, (void*)out, nullptr);
}